// Round 6
// baseline (143.641 us; speedup 1.0000x reference)
//
#include <hip/hip_runtime.h>

#define NN 500
#define SLOPEC 0.01f

typedef unsigned short us;
typedef unsigned int u32;
typedef unsigned long long u64;

// ---- canonical fp32 copies of all inputs + scratch, as device globals ----
__device__ __align__(16) float g_imf[16000];
__device__ __align__(16) float g_c[1504];
__device__ __align__(16) float g_ct[1504];
__device__ __align__(16) float g_wc1[2048];
__device__ __align__(16) float g_bc1[64];
__device__ __align__(16) float g_wc2[8192];
__device__ __align__(16) float g_bc2[128];
__device__ __align__(16) float g_wps1[32768];
__device__ __align__(16) float g_bps1[256];
__device__ __align__(16) float g_wps2[32768];
__device__ __align__(16) float g_bps2[128];
__device__ __align__(16) float g_wp1[192];
__device__ __align__(16) float g_bp1[64];
__device__ __align__(16) float g_wp2[8192];
__device__ __align__(16) float g_bp2[128];
__device__ __align__(16) float g_wfc1[16384];
__device__ __align__(16) float g_bfc1[64];
__device__ __align__(16) float g_wfc2[10240];
__device__ __align__(16) float g_bfc2[64];
__device__ __align__(16) float g_wfc[8192];
__device__ __align__(16) float g_bfc[64];

__device__ __align__(16) float g_cfw[NN*128];
__device__ __align__(16) float g_Yw[NN*128];
__device__ __align__(16) float g_Zw[NN*128];
__device__ float g_wA[4000];     // exp(-dist), normalized in k3
__device__ float g_wB[4000];
__device__ float g_sumA;
__device__ float g_sumB;
__device__ int   g_inds[4000];
__device__ int   g_inds_tc[4000];
__device__ int   g_isf32;

__device__ __forceinline__ float b2f(us u){ return __uint_as_float(((u32)u)<<16); }
__device__ __forceinline__ us f2b(float f){
  u32 u = __float_as_uint(f);
  u32 r = u + 0x7fffu + ((u>>16)&1u);
  return (us)(r>>16);
}
__device__ __forceinline__ float lrelu(float x){ return x >= 0.f ? x : SLOPEC*x; }
__device__ __forceinline__ float dot4(const float4 w, const float* h){
  return w.x*h[0] + w.y*h[1] + w.z*h[2] + w.w*h[3];
}
__device__ __forceinline__ int clampi(int v){ return v < 0 ? 0 : (v >= NN ? NN-1 : v); }

// K0: detect input dtype (fp32 vs bf16) from img_feat bit patterns, then
// convert every input into canonical fp32 device-global arrays.
// Also zeroes the softmax accumulator scalars (device globals persist
// across launches; harness only poisons d_out/d_ws).
__global__ __launch_bounds__(256) void k0(
    const void* in0, const void* in1, const void* in2, const void* in3,
    const void* in4, const void* in5, const void* in6, const void* in7,
    const void* in8, const void* in9, const void* in10, const void* in11,
    const void* in12, const void* in13, const void* in14, const void* in15,
    const void* in16, const void* in17, const void* in18, const void* in19,
    const void* in20)
{
  __shared__ int sflag;
  const int tid = threadIdx.x;
  if (blockIdx.x == 0 && tid == 0){ g_sumA = 0.f; g_sumB = 0.f; }
  if (tid < 64){
    const us* u = (const us*)in0;
    int cnt = 0;
    #pragma unroll
    for (int j = 0; j < 8; ++j){
      us v = u[2*(tid*8+j)];          // even us-index: fp32 low-halves if fp32
      int e = (v >> 7) & 0xff;
      cnt += (e >= 143);              // |x| >= 2^16 as bf16: impossible for real data
    }
    #pragma unroll
    for (int off = 32; off; off >>= 1) cnt += __shfl_xor(cnt, off);
    if (tid == 0){ sflag = (cnt > 16); g_isf32 = (cnt > 16); }
  }
  __syncthreads();
  const int isf32 = sflag;
  const int g0 = blockIdx.x*256 + tid;
  const int gs = gridDim.x*256;
  #define CVT(src, dst, n) \
    for (int i = g0; i < (n); i += gs) \
      dst[i] = isf32 ? ((const float*)(src))[i] : b2f(((const us*)(src))[i]);
  CVT(in0,  g_imf, 16000)
  CVT(in1,  g_c,   1500)
  CVT(in2,  g_ct,  1500)
  CVT(in3,  g_wc1, 2048)
  CVT(in4,  g_bc1, 64)
  CVT(in5,  g_wc2, 8192)
  CVT(in6,  g_bc2, 128)
  CVT(in7,  g_wps1,32768)
  CVT(in8,  g_bps1,256)
  CVT(in9,  g_wps2,32768)
  CVT(in10, g_bps2,128)
  CVT(in11, g_wp1, 192)
  CVT(in12, g_bp1, 64)
  CVT(in13, g_wp2, 8192)
  CVT(in14, g_bp2, 128)
  CVT(in15, g_wfc1,16384)
  CVT(in16, g_bfc1,64)
  CVT(in17, g_wfc2,10240)
  CVT(in18, g_bfc2,64)
  CVT(in19, g_wfc, 8192)
  CVT(in20, g_bfc, 64)
  #undef CVT
}

// K1: blocks 0..249   = KNN (1 query per wave, 4/block) + exp(-dist) weights
//                       + per-wave atomicAdd into the global softmax sum
//                       (no max-shift needed: logits in [-~10,0], exp safe).
//     blocks 250..749 = per-point conv chains, ONE point per block.
__global__ __launch_bounds__(256) void k1()
{
  __shared__ __align__(16) float sm[1504];
  const int tid = threadIdx.x;
  const int b = blockIdx.x;
  if (b < 250) {
    // ---------------- KNN + exp weights ----------------
    const int dir = (b >= 125);            // 0: query=c, ref=ct ; 1: query=ct, ref=c
    const float* refp = dir ? g_c : g_ct;
    const float* qp   = dir ? g_ct : g_c;
    int* outp = dir ? g_inds_tc : g_inds;
    float* wp = dir ? g_wB : g_wA;
    float* sump = dir ? &g_sumB : &g_sumA;
    for (int e = tid; e < 1500; e += 256) sm[e] = refp[e];
    __syncthreads();
    const int lane = tid & 63;
    const int wv = tid >> 6;
    const int q = b*4 + wv;
    const int qi = q - (dir ? 500 : 0);
    float qx = qp[qi*3+0], qy = qp[qi*3+1], qz = qp[qi*3+2];
    // exact numpy op order: sum(q^2) - 2*dot + sum(r^2)
    float sq = __fadd_rn(__fadd_rn(__fmul_rn(qx,qx),__fmul_rn(qy,qy)),__fmul_rn(qz,qz));
    const u64 SENT = 0xFFFFFFFF00000000ull;   // sentinel carries valid idx 0
    u64 a0=SENT,a1=SENT,a2=SENT,a3=SENT,a4=SENT,a5=SENT,a6=SENT,a7=SENT;
    for (int j = lane; j < NN; j += 64){
      float rx = sm[j*3+0], ry = sm[j*3+1], rz = sm[j*3+2];
      float dt = __fadd_rn(__fadd_rn(__fmul_rn(qx,rx),__fmul_rn(qy,ry)),__fmul_rn(qz,rz));
      float sr = __fadd_rn(__fadd_rn(__fmul_rn(rx,rx),__fmul_rn(ry,ry)),__fmul_rn(rz,rz));
      float d2 = __fadd_rn(__fsub_rn(sq, __fmul_rn(2.f,dt)), sr);
      u32 fb = __float_as_uint(d2);
      fb = (fb & 0x80000000u) ? ~fb : (fb | 0x80000000u);   // monotone float->uint
      u64 key = ((u64)fb << 32) | (u32)j;
      if (key < a0){ u64 t=a0; a0=key; key=t; }
      if (key < a1){ u64 t=a1; a1=key; key=t; }
      if (key < a2){ u64 t=a2; a2=key; key=t; }
      if (key < a3){ u64 t=a3; a3=key; key=t; }
      if (key < a4){ u64 t=a4; a4=key; key=t; }
      if (key < a5){ u64 t=a5; a5=key; key=t; }
      if (key < a6){ u64 t=a6; a6=key; key=t; }
      if (key < a7){ u64 t=a7; a7=key; key=t; }
    }
    float wsum = 0.f;
    #pragma unroll
    for (int r8 = 0; r8 < 8; ++r8){
      u64 m = a0;
      #pragma unroll
      for (int off = 32; off; off >>= 1){
        u64 o = __shfl_xor(m, off);
        if (o < m) m = o;
      }
      bool mine = (a0 == m);
      a0 = mine ? a1 : a0;  a1 = mine ? a2 : a1;  a2 = mine ? a3 : a2;
      a3 = mine ? a4 : a3;  a4 = mine ? a5 : a4;  a5 = mine ? a6 : a5;
      a6 = mine ? a7 : a6;  a7 = mine ? SENT : a7;
      if (lane == 0){
        int idx = (int)(m & 0xffffffffu);
        outp[qi*8 + r8] = idx;
        // softmax numerator, reference dist order: sqrt((dx^2+dy^2)+dz^2)
        float rx = sm[idx*3+0], ry = sm[idx*3+1], rz = sm[idx*3+2];
        float dx = __fsub_rn(qx,rx), dy = __fsub_rn(qy,ry), dz = __fsub_rn(qz,rz);
        float s2 = __fadd_rn(__fadd_rn(__fmul_rn(dx,dx),__fmul_rn(dy,dy)),__fmul_rn(dz,dz));
        float ev = expf(-sqrtf(s2));
        wp[qi*8 + r8] = ev;
        wsum += ev;
      }
    }
    if (lane == 0) atomicAdd(sump, wsum);
  } else {
    // ---------------- per-point chain, one point ----------------
    const int p = b - 250;
    float* sx  = sm;          // 3   (c column)
    float* sxi = sm + 4;      // 32  (imf column)
    float* h1  = sm + 64;     // 64
    float* cf  = sm + 128;    // 128
    float* h2  = sm + 256;    // 256
    float* hy  = sm + 512;    // 64
    if (tid < 3)  sx[tid] = g_c[p*3 + tid];
    if (tid >= 32 && tid < 64) sxi[tid-32] = g_imf[(tid-32)*NN + p];
    __syncthreads();
    // stage1: h1 = lrelu(pconv1 @ x + b)   (threads 0..63)
    if (tid < 64){
      float acc = g_bp1[tid];
      acc += g_wp1[tid*3+0]*sx[0];
      acc += g_wp1[tid*3+1]*sx[1];
      acc += g_wp1[tid*3+2]*sx[2];
      h1[tid] = lrelu(acc);
    }
    __syncthreads();
    // stage2 (t0..127): cf = pconv2 @ h1 + b  (dot64)
    // stage5 (t128..191): hy = lrelu(conv1 @ imf + b)  (dot32) — independent
    if (tid < 128){
      int r = tid;
      float ac0 = g_bp2[r], ac1 = 0.f;
      const float4* wrow = (const float4*)(g_wp2 + (size_t)r*64);
      #pragma unroll 8
      for (int c4=0; c4<16; c4+=2){
        ac0 += dot4(wrow[c4],   h1 + c4*4);
        ac1 += dot4(wrow[c4+1], h1 + c4*4 + 4);
      }
      float acc = ac0 + ac1;
      cf[r] = acc;
      g_cfw[(size_t)p*128 + r] = acc;
    } else if (tid < 192){
      int r = tid - 128;
      float acc = g_bc1[r];
      const float4* wrow = (const float4*)(g_wc1 + (size_t)r*32);
      #pragma unroll 8
      for (int c4=0; c4<8; ++c4) acc += dot4(wrow[c4], sxi + c4*4);
      hy[r] = lrelu(acc);
    }
    __syncthreads();
    // stage3 (all 256): h2 = lrelu(psconv1 @ cf + b)  (dot128, dual acc)
    {
      float ac0 = g_bps1[tid], ac1 = 0.f;
      const float4* wrow = (const float4*)(g_wps1 + (size_t)tid*128);
      #pragma unroll 8
      for (int c4=0; c4<32; c4+=2){
        ac0 += dot4(wrow[c4],   cf + c4*4);
        ac1 += dot4(wrow[c4+1], cf + c4*4 + 4);
      }
      h2[tid] = lrelu(ac0 + ac1);
    }
    __syncthreads();
    // stage4 (t0..127): Z = psconv2 @ h2 + b  (dot256, dual acc)
    // stage6 (t128..255): Y = conv2 @ hy + b  (dot64)
    if (tid < 128){
      int r = tid;
      float ac0 = g_bps2[r], ac1 = 0.f;
      const float4* wrow = (const float4*)(g_wps2 + (size_t)r*256);
      #pragma unroll 8
      for (int c4=0; c4<64; c4+=2){
        ac0 += dot4(wrow[c4],   h2 + c4*4);
        ac1 += dot4(wrow[c4+1], h2 + c4*4 + 4);
      }
      g_Zw[(size_t)p*128 + r] = ac0 + ac1;
    } else {
      int r = tid - 128;
      float ac0 = g_bc2[r], ac1 = 0.f;
      const float4* wrow = (const float4*)(g_wc2 + (size_t)r*64);
      #pragma unroll 8
      for (int c4=0; c4<16; c4+=2){
        ac0 += dot4(wrow[c4],   hy + c4*4);
        ac1 += dot4(wrow[c4+1], hy + c4*4 + 4);
      }
      g_Yw[(size_t)p*128 + r] = ac0 + ac1;
    }
  }
}

// K3: ONE point per block (500 blocks): weighted gather-mean + fc chain -> out.
// Softmax weights finalized here: w = g_w*[gi] / g_sum* (k1 wrote exp + sums).
__global__ __launch_bounds__(256) void k3(void* outv)
{
  __shared__ __align__(16) float sm[592];
  float* sb1 = sm;          // 256 : [sf | cf]
  float* sb2 = sm + 256;    // 160 : [sfp | imf]
  float* sg  = sm + 416;    // 128 : lrelu([f2 ; f1])
  float* swa = sm + 544;    // 8
  float* swb = sm + 552;    // 8
  int* sia = (int*)(sm + 560);  // 8
  int* sib = (int*)(sm + 568);  // 8
  const int tid = threadIdx.x;
  const int p = blockIdx.x;
  const int of32 = g_isf32;
  if (tid < 8){
    sia[tid] = clampi(g_inds[p*8 + tid]);    swa[tid] = g_wA[p*8 + tid] / g_sumA;
    sib[tid] = clampi(g_inds_tc[p*8 + tid]); swb[tid] = g_wB[p*8 + tid] / g_sumB;
  }
  if (tid >= 64 && tid < 192) sb1[128 + (tid-64)] = g_cfw[(size_t)p*128 + (tid-64)];
  if (tid >= 192 && tid < 224) sb2[128 + (tid-192)] = g_imf[(tid-192)*NN + p];
  __syncthreads();
  // gather-mean: t0..127 -> sf (from Y), t128..255 -> sfp (from Z)
  if (tid < 128){
    int r = tid;
    float acc = 0.f;
    #pragma unroll
    for (int j=0;j<8;++j) acc += swa[j] * g_Yw[(size_t)sia[j]*128 + r];
    sb1[r] = acc * 0.125f;
  } else {
    int r = tid - 128;
    float acc = 0.f;
    #pragma unroll
    for (int j=0;j<8;++j) acc += swb[j] * g_Zw[(size_t)sib[j]*128 + r];
    sb2[r] = acc * 0.125f;
  }
  __syncthreads();
  // f1 (t0..63, dot256, dual acc) ; f2 (t64..127, dot160); g = lrelu([f2 ; f1])
  if (tid < 64){
    int r = tid;
    float a0 = g_bfc1[r], a1 = 0.f;
    const float4* w1 = (const float4*)(g_wfc1 + (size_t)r*256);
    #pragma unroll 8
    for (int c4=0; c4<64; c4+=2){
      a0 += dot4(w1[c4],   sb1 + c4*4);
      a1 += dot4(w1[c4+1], sb1 + c4*4 + 4);
    }
    sg[64 + r] = lrelu(a0 + a1);
  } else if (tid < 128){
    int r = tid - 64;
    float a0 = g_bfc2[r], a1 = 0.f;
    const float4* w2 = (const float4*)(g_wfc2 + (size_t)r*160);
    #pragma unroll 8
    for (int c4=0; c4<40; c4+=2){
      a0 += dot4(w2[c4],   sb2 + c4*4);
      a1 += dot4(w2[c4+1], sb2 + c4*4 + 4);
    }
    sg[r] = lrelu(a0 + a1);
  }
  __syncthreads();
  // out = wfc @ g + b (t0..63, dot128, dual acc)
  if (tid < 64){
    int r = tid;
    float a0 = g_bfc[r], a1 = 0.f;
    const float4* w3 = (const float4*)(g_wfc + (size_t)r*128);
    #pragma unroll 8
    for (int c4=0; c4<32; c4+=2){
      a0 += dot4(w3[c4],   sg + c4*4);
      a1 += dot4(w3[c4+1], sg + c4*4 + 4);
    }
    float a = a0 + a1;
    if (of32) ((float*)outv)[r*NN + p] = a;
    else      ((us*)outv)[r*NN + p] = f2b(a);
  }
}

extern "C" void kernel_launch(void* const* d_in, const int* in_sizes, int n_in,
                              void* d_out, int out_size, void* d_ws, size_t ws_size,
                              hipStream_t stream)
{
  (void)d_ws; (void)ws_size; (void)in_sizes; (void)n_in; (void)out_size;
  k0<<<64, 256, 0, stream>>>(
    d_in[0], d_in[1], d_in[2], d_in[3], d_in[4], d_in[5], d_in[6],
    d_in[7], d_in[8], d_in[9], d_in[10], d_in[11], d_in[12], d_in[13],
    d_in[14], d_in[15], d_in[16], d_in[17], d_in[18], d_in[19], d_in[20]);
  k1<<<750, 256, 0, stream>>>();
  k3<<<500, 256, 0, stream>>>(d_out);
}

// Round 9
// 134.180 us; speedup vs baseline: 1.0705x; 1.0705x over previous
//
#include <hip/hip_runtime.h>

#define NN 500
#define SLOPEC 0.01f

typedef unsigned short us;
typedef unsigned int u32;
typedef unsigned long long u64;

// ---- canonical fp32 copies of all inputs + scratch, as device globals ----
// (16B-aligned by construction: safe for float4 loads. Harness input buffers
//  are NOT guaranteed 16B-aligned — rounds 1/2/8 NaN'd on uint4 input loads —
//  so inputs are only ever read with scalar us/float loads, in k0.)
__device__ __align__(16) float g_imf[16000];
__device__ __align__(16) float g_c[1504];
__device__ __align__(16) float g_ct[1504];
__device__ __align__(16) float g_wc1[2048];
__device__ __align__(16) float g_bc1[64];
__device__ __align__(16) float g_wc2[8192];
__device__ __align__(16) float g_bc2[128];
__device__ __align__(16) float g_wps1[32768];
__device__ __align__(16) float g_bps1[256];
__device__ __align__(16) float g_wps2[32768];
__device__ __align__(16) float g_bps2[128];
__device__ __align__(16) float g_wp1[192];
__device__ __align__(16) float g_bp1[64];
__device__ __align__(16) float g_wp2[8192];
__device__ __align__(16) float g_bp2[128];
__device__ __align__(16) float g_wfc1[16384];
__device__ __align__(16) float g_bfc1[64];
__device__ __align__(16) float g_wfc2[10240];
__device__ __align__(16) float g_bfc2[64];
__device__ __align__(16) float g_wfc[8192];
__device__ __align__(16) float g_bfc[64];

__device__ __align__(16) float g_cfw[NN*128];
__device__ __align__(16) float g_Yw[NN*128];
__device__ __align__(16) float g_Zw[NN*128];
__device__ float g_logA[4000];
__device__ float g_logB[4000];
__device__ float g_wA[4000];
__device__ float g_wB[4000];
__device__ int   g_inds[4000];
__device__ int   g_inds_tc[4000];
__device__ int   g_isf32;

__device__ __forceinline__ float b2f(us u){ return __uint_as_float(((u32)u)<<16); }
__device__ __forceinline__ us f2b(float f){
  u32 u = __float_as_uint(f);
  u32 r = u + 0x7fffu + ((u>>16)&1u);
  return (us)(r>>16);
}
__device__ __forceinline__ float lrelu(float x){ return x >= 0.f ? x : SLOPEC*x; }
__device__ __forceinline__ float dot4(const float4 w, const float* h){
  return w.x*h[0] + w.y*h[1] + w.z*h[2] + w.w*h[3];
}
__device__ __forceinline__ int clampi(int v){ return v < 0 ? 0 : (v >= NN ? NN-1 : v); }

// K0: detect input dtype (fp32 vs bf16) from img_feat bit patterns, then
// convert every input into canonical fp32 device-global arrays (scalar loads).
__global__ __launch_bounds__(256) void k0(
    const void* in0, const void* in1, const void* in2, const void* in3,
    const void* in4, const void* in5, const void* in6, const void* in7,
    const void* in8, const void* in9, const void* in10, const void* in11,
    const void* in12, const void* in13, const void* in14, const void* in15,
    const void* in16, const void* in17, const void* in18, const void* in19,
    const void* in20)
{
  __shared__ int sflag;
  const int tid = threadIdx.x;
  if (tid < 64){
    const us* u = (const us*)in0;
    int cnt = 0;
    #pragma unroll
    for (int j = 0; j < 8; ++j){
      us v = u[2*(tid*8+j)];          // even us-index: fp32 low-halves if fp32
      int e = (v >> 7) & 0xff;
      cnt += (e >= 143);              // |x| >= 2^16 as bf16: impossible for real data
    }
    #pragma unroll
    for (int off = 32; off; off >>= 1) cnt += __shfl_xor(cnt, off);
    if (tid == 0){ sflag = (cnt > 16); g_isf32 = (cnt > 16); }
  }
  __syncthreads();
  const int isf32 = sflag;
  const int g0 = blockIdx.x*256 + tid;
  const int gs = gridDim.x*256;
  #define CVT(src, dst, n) \
    for (int i = g0; i < (n); i += gs) \
      dst[i] = isf32 ? ((const float*)(src))[i] : b2f(((const us*)(src))[i]);
  CVT(in0,  g_imf, 16000)
  CVT(in1,  g_c,   1500)
  CVT(in2,  g_ct,  1500)
  CVT(in3,  g_wc1, 2048)
  CVT(in4,  g_bc1, 64)
  CVT(in5,  g_wc2, 8192)
  CVT(in6,  g_bc2, 128)
  CVT(in7,  g_wps1,32768)
  CVT(in8,  g_bps1,256)
  CVT(in9,  g_wps2,32768)
  CVT(in10, g_bps2,128)
  CVT(in11, g_wp1, 192)
  CVT(in12, g_bp1, 64)
  CVT(in13, g_wp2, 8192)
  CVT(in14, g_bp2, 128)
  CVT(in15, g_wfc1,16384)
  CVT(in16, g_bfc1,64)
  CVT(in17, g_wfc2,10240)
  CVT(in18, g_bfc2,64)
  CVT(in19, g_wfc, 8192)
  CVT(in20, g_bfc, 64)
  #undef CVT
}

// K1: blocks 0..249   = KNN (1 query per wave, 4/block) + logit emission.
//     blocks 250..749 = per-point conv chains, ONE point per block.
__global__ __launch_bounds__(256) void k1()
{
  __shared__ __align__(16) float sm[1504];
  const int tid = threadIdx.x;
  const int b = blockIdx.x;
  if (b < 250) {
    // ---------------- KNN + logits ----------------
    const int dir = (b >= 125);            // 0: query=c, ref=ct ; 1: query=ct, ref=c
    const float* refp = dir ? g_c : g_ct;
    const float* qp   = dir ? g_ct : g_c;
    int* outp = dir ? g_inds_tc : g_inds;
    float* logp = dir ? g_logB : g_logA;
    for (int e = tid; e < 1500; e += 256) sm[e] = refp[e];
    __syncthreads();
    const int lane = tid & 63;
    const int wv = tid >> 6;
    const int q = b*4 + wv;
    const int qi = q - (dir ? 500 : 0);
    float qx = qp[qi*3+0], qy = qp[qi*3+1], qz = qp[qi*3+2];
    // exact numpy op order: sum(q^2) - 2*dot + sum(r^2)
    float sq = __fadd_rn(__fadd_rn(__fmul_rn(qx,qx),__fmul_rn(qy,qy)),__fmul_rn(qz,qz));
    const u64 SENT = 0xFFFFFFFF00000000ull;   // sentinel carries valid idx 0
    u64 a0=SENT,a1=SENT,a2=SENT,a3=SENT,a4=SENT,a5=SENT,a6=SENT,a7=SENT;
    for (int j = lane; j < NN; j += 64){
      float rx = sm[j*3+0], ry = sm[j*3+1], rz = sm[j*3+2];
      float dt = __fadd_rn(__fadd_rn(__fmul_rn(qx,rx),__fmul_rn(qy,ry)),__fmul_rn(qz,rz));
      float sr = __fadd_rn(__fadd_rn(__fmul_rn(rx,rx),__fmul_rn(ry,ry)),__fmul_rn(rz,rz));
      float d2 = __fadd_rn(__fsub_rn(sq, __fmul_rn(2.f,dt)), sr);
      u32 fb = __float_as_uint(d2);
      fb = (fb & 0x80000000u) ? ~fb : (fb | 0x80000000u);   // monotone float->uint
      u64 key = ((u64)fb << 32) | (u32)j;
      if (key < a0){ u64 t=a0; a0=key; key=t; }
      if (key < a1){ u64 t=a1; a1=key; key=t; }
      if (key < a2){ u64 t=a2; a2=key; key=t; }
      if (key < a3){ u64 t=a3; a3=key; key=t; }
      if (key < a4){ u64 t=a4; a4=key; key=t; }
      if (key < a5){ u64 t=a5; a5=key; key=t; }
      if (key < a6){ u64 t=a6; a6=key; key=t; }
      if (key < a7){ u64 t=a7; a7=key; key=t; }
    }
    #pragma unroll
    for (int r8 = 0; r8 < 8; ++r8){
      u64 m = a0;
      #pragma unroll
      for (int off = 32; off; off >>= 1){
        u64 o = __shfl_xor(m, off);
        if (o < m) m = o;
      }
      bool mine = (a0 == m);
      a0 = mine ? a1 : a0;  a1 = mine ? a2 : a1;  a2 = mine ? a3 : a2;
      a3 = mine ? a4 : a3;  a4 = mine ? a5 : a4;  a5 = mine ? a6 : a5;
      a6 = mine ? a7 : a6;  a7 = mine ? SENT : a7;
      if (lane == 0){
        int idx = (int)(m & 0xffffffffu);
        outp[qi*8 + r8] = idx;
        // softmax logit, reference order: -sqrt((dx^2+dy^2)+dz^2)
        float rx = sm[idx*3+0], ry = sm[idx*3+1], rz = sm[idx*3+2];
        float dx = __fsub_rn(qx,rx), dy = __fsub_rn(qy,ry), dz = __fsub_rn(qz,rz);
        float s2 = __fadd_rn(__fadd_rn(__fmul_rn(dx,dx),__fmul_rn(dy,dy)),__fmul_rn(dz,dz));
        logp[qi*8 + r8] = -sqrtf(s2);
      }
    }
  } else {
    // ---------------- per-point chain, one point ----------------
    const int p = b - 250;
    float* sx  = sm;          // 3   (c column)
    float* sxi = sm + 4;      // 32  (imf column)
    float* h1  = sm + 64;     // 64
    float* cf  = sm + 128;    // 128
    float* h2  = sm + 256;    // 256
    float* hy  = sm + 512;    // 64
    if (tid < 3)  sx[tid] = g_c[p*3 + tid];
    if (tid >= 32 && tid < 64) sxi[tid-32] = g_imf[(tid-32)*NN + p];
    __syncthreads();
    // stage1: h1 = lrelu(pconv1 @ x + b)   (threads 0..63)
    if (tid < 64){
      float acc = g_bp1[tid];
      acc += g_wp1[tid*3+0]*sx[0];
      acc += g_wp1[tid*3+1]*sx[1];
      acc += g_wp1[tid*3+2]*sx[2];
      h1[tid] = lrelu(acc);
    }
    __syncthreads();
    // stage2 (t0..127): cf = pconv2 @ h1 + b  (dot64)
    // stage5 (t128..191): hy = lrelu(conv1 @ imf + b)  (dot32) — independent
    if (tid < 128){
      int r = tid;
      float acc = g_bp2[r];
      const float4* wrow = (const float4*)(g_wp2 + (size_t)r*64);
      #pragma unroll 8
      for (int c4=0; c4<16; ++c4) acc += dot4(wrow[c4], h1 + c4*4);
      cf[r] = acc;
      g_cfw[(size_t)p*128 + r] = acc;
    } else if (tid < 192){
      int r = tid - 128;
      float acc = g_bc1[r];
      const float4* wrow = (const float4*)(g_wc1 + (size_t)r*32);
      #pragma unroll 8
      for (int c4=0; c4<8; ++c4) acc += dot4(wrow[c4], sxi + c4*4);
      hy[r] = lrelu(acc);
    }
    __syncthreads();
    // stage3 (all 256): h2 = lrelu(psconv1 @ cf + b)  (dot128)
    {
      float acc = g_bps1[tid];
      const float4* wrow = (const float4*)(g_wps1 + (size_t)tid*128);
      #pragma unroll 8
      for (int c4=0; c4<32; ++c4) acc += dot4(wrow[c4], cf + c4*4);
      h2[tid] = lrelu(acc);
    }
    __syncthreads();
    // stage4 (t0..127): Z = psconv2 @ h2 + b  (dot256)
    // stage6 (t128..255): Y = conv2 @ hy + b  (dot64)
    if (tid < 128){
      int r = tid;
      float acc = g_bps2[r];
      const float4* wrow = (const float4*)(g_wps2 + (size_t)r*256);
      #pragma unroll 8
      for (int c4=0; c4<64; ++c4) acc += dot4(wrow[c4], h2 + c4*4);
      g_Zw[(size_t)p*128 + r] = acc;
    } else {
      int r = tid - 128;
      float acc = g_bc2[r];
      const float4* wrow = (const float4*)(g_wc2 + (size_t)r*64);
      #pragma unroll 8
      for (int c4=0; c4<16; ++c4) acc += dot4(wrow[c4], hy + c4*4);
      g_Yw[(size_t)p*128 + r] = acc;
    }
  }
}

// K2: global softmax over the 4000 precomputed logits, one block per direction.
__global__ __launch_bounds__(1024) void k2()
{
  const int dir = blockIdx.x;
  const float* lg_in = dir ? g_logB : g_logA;
  float* wout = dir ? g_wB : g_wA;
  const int tid = threadIdx.x;
  const int lane = tid & 63, wv = tid >> 6;
  __shared__ float red1[16];
  __shared__ float red2[16];
  float lg[4];
  #pragma unroll
  for (int k=0;k<4;++k){
    int e = tid + 1024*k;
    lg[k] = (e < 4000) ? lg_in[e] : -INFINITY;
  }
  float m = fmaxf(fmaxf(lg[0],lg[1]), fmaxf(lg[2],lg[3]));
  #pragma unroll
  for (int off=32; off; off>>=1) m = fmaxf(m, __shfl_xor(m, off));
  if (lane == 0) red1[wv] = m;
  __syncthreads();
  if (tid == 0){
    float mm = red1[0];
    #pragma unroll
    for (int i=1;i<16;++i) mm = fmaxf(mm, red1[i]);
    red1[0] = mm;
  }
  __syncthreads();
  float gmax = red1[0];
  float ex[4];
  float s = 0.f;
  #pragma unroll
  for (int k=0;k<4;++k){
    int e = tid + 1024*k;
    ex[k] = (e < 4000) ? expf(lg[k] - gmax) : 0.f;
    s += ex[k];
  }
  #pragma unroll
  for (int off=32; off; off>>=1) s += __shfl_xor(s, off);
  if (lane == 0) red2[wv] = s;
  __syncthreads();
  if (tid == 0){
    float ss = 0.f;
    #pragma unroll
    for (int i=0;i<16;++i) ss += red2[i];
    red2[0] = ss;
  }
  __syncthreads();
  float gsum = red2[0];
  #pragma unroll
  for (int k=0;k<4;++k){
    int e = tid + 1024*k;
    if (e < 4000) wout[e] = ex[k] / gsum;
  }
}

// K3: ONE point per block (500 blocks): weighted gather-mean + fc chain -> out.
__global__ __launch_bounds__(256) void k3(void* outv)
{
  __shared__ __align__(16) float sm[592];
  float* sb1 = sm;          // 256 : [sf | cf]
  float* sb2 = sm + 256;    // 160 : [sfp | imf]
  float* sg  = sm + 416;    // 128 : lrelu([f2 ; f1])
  float* swa = sm + 544;    // 8
  float* swb = sm + 552;    // 8
  int* sia = (int*)(sm + 560);  // 8
  int* sib = (int*)(sm + 568);  // 8
  const int tid = threadIdx.x;
  const int p = blockIdx.x;
  const int of32 = g_isf32;
  if (tid < 8){
    sia[tid] = clampi(g_inds[p*8 + tid]);    swa[tid] = g_wA[p*8 + tid];
    sib[tid] = clampi(g_inds_tc[p*8 + tid]); swb[tid] = g_wB[p*8 + tid];
  }
  if (tid >= 64 && tid < 192) sb1[128 + (tid-64)] = g_cfw[(size_t)p*128 + (tid-64)];
  if (tid >= 192 && tid < 224) sb2[128 + (tid-192)] = g_imf[(tid-192)*NN + p];
  __syncthreads();
  // gather-mean: t0..127 -> sf (from Y), t128..255 -> sfp (from Z)
  if (tid < 128){
    int r = tid;
    float acc = 0.f;
    #pragma unroll
    for (int j=0;j<8;++j) acc += swa[j] * g_Yw[(size_t)sia[j]*128 + r];
    sb1[r] = acc * 0.125f;
  } else {
    int r = tid - 128;
    float acc = 0.f;
    #pragma unroll
    for (int j=0;j<8;++j) acc += swb[j] * g_Zw[(size_t)sib[j]*128 + r];
    sb2[r] = acc * 0.125f;
  }
  __syncthreads();
  // f1 (t0..63, dot256) ; f2 (t64..127, dot160); g = lrelu([f2 ; f1])
  if (tid < 64){
    int r = tid;
    float a1 = g_bfc1[r];
    const float4* w1 = (const float4*)(g_wfc1 + (size_t)r*256);
    #pragma unroll 8
    for (int c4=0; c4<64; ++c4) a1 += dot4(w1[c4], sb1 + c4*4);
    sg[64 + r] = lrelu(a1);
  } else if (tid < 128){
    int r = tid - 64;
    float a2 = g_bfc2[r];
    const float4* w2 = (const float4*)(g_wfc2 + (size_t)r*160);
    #pragma unroll 8
    for (int c4=0; c4<40; ++c4) a2 += dot4(w2[c4], sb2 + c4*4);
    sg[r] = lrelu(a2);
  }
  __syncthreads();
  // out = wfc @ g + b (t0..63, dot128)
  if (tid < 64){
    int r = tid;
    float a = g_bfc[r];
    const float4* w3 = (const float4*)(g_wfc + (size_t)r*128);
    #pragma unroll 8
    for (int c4=0; c4<32; ++c4) a += dot4(w3[c4], sg + c4*4);
    if (of32) ((float*)outv)[r*NN + p] = a;
    else      ((us*)outv)[r*NN + p] = f2b(a);
  }
}

extern "C" void kernel_launch(void* const* d_in, const int* in_sizes, int n_in,
                              void* d_out, int out_size, void* d_ws, size_t ws_size,
                              hipStream_t stream)
{
  (void)d_ws; (void)ws_size; (void)in_sizes; (void)n_in; (void)out_size;
  k0<<<64, 256, 0, stream>>>(
    d_in[0], d_in[1], d_in[2], d_in[3], d_in[4], d_in[5], d_in[6],
    d_in[7], d_in[8], d_in[9], d_in[10], d_in[11], d_in[12], d_in[13],
    d_in[14], d_in[15], d_in[16], d_in[17], d_in[18], d_in[19], d_in[20]);
  k1<<<750, 256, 0, stream>>>();
  k2<<<2, 1024, 0, stream>>>();
  k3<<<500, 256, 0, stream>>>(d_out);
}

// Round 10
// 130.828 us; speedup vs baseline: 1.0979x; 1.0256x over previous
//
#include <hip/hip_runtime.h>

#define NN 500
#define SLOPEC 0.01f

typedef unsigned short us;
typedef unsigned int u32;
typedef unsigned long long u64;

// ---- canonical fp32 copies of all inputs + scratch, as device globals ----
// (16B-aligned by construction: safe for float4 loads. Harness input buffers
//  are NOT guaranteed 16B-aligned — rounds 1/2/8 NaN'd on uint4 input loads —
//  so inputs are only ever read with scalar us/float loads, in k0.)
__device__ __align__(16) float g_imf[16000];
__device__ __align__(16) float g_c[1504];
__device__ __align__(16) float g_ct[1504];
__device__ __align__(16) float g_wc1[2048];
__device__ __align__(16) float g_bc1[64];
__device__ __align__(16) float g_wc2[8192];
__device__ __align__(16) float g_bc2[128];
__device__ __align__(16) float g_wps1[32768];
__device__ __align__(16) float g_bps1[256];
__device__ __align__(16) float g_wps2[32768];
__device__ __align__(16) float g_bps2[128];
__device__ __align__(16) float g_wp1[192];
__device__ __align__(16) float g_bp1[64];
__device__ __align__(16) float g_wp2[8192];
__device__ __align__(16) float g_bp2[128];
__device__ __align__(16) float g_wfc1[16384];
__device__ __align__(16) float g_bfc1[64];
__device__ __align__(16) float g_wfc2[10240];
__device__ __align__(16) float g_bfc2[64];
__device__ __align__(16) float g_wfc[8192];
__device__ __align__(16) float g_bfc[64];

__device__ __align__(16) float g_cfw[NN*128];
__device__ __align__(16) float g_Yw[NN*128];
__device__ __align__(16) float g_Zw[NN*128];
__device__ __align__(16) float g_logA[4000];   // exp(-dist) numerators (k1)
__device__ __align__(16) float g_logB[4000];
__device__ int   g_inds[4000];
__device__ int   g_inds_tc[4000];
__device__ int   g_isf32;

__device__ __forceinline__ float b2f(us u){ return __uint_as_float(((u32)u)<<16); }
__device__ __forceinline__ us f2b(float f){
  u32 u = __float_as_uint(f);
  u32 r = u + 0x7fffu + ((u>>16)&1u);
  return (us)(r>>16);
}
__device__ __forceinline__ float lrelu(float x){ return x >= 0.f ? x : SLOPEC*x; }
__device__ __forceinline__ float dot4(const float4 w, const float* h){
  return w.x*h[0] + w.y*h[1] + w.z*h[2] + w.w*h[3];
}
__device__ __forceinline__ int clampi(int v){ return v < 0 ? 0 : (v >= NN ? NN-1 : v); }

// K0: detect input dtype (fp32 vs bf16) from img_feat bit patterns, then
// convert every input into canonical fp32 device-global arrays (scalar loads).
__global__ __launch_bounds__(256) void k0(
    const void* in0, const void* in1, const void* in2, const void* in3,
    const void* in4, const void* in5, const void* in6, const void* in7,
    const void* in8, const void* in9, const void* in10, const void* in11,
    const void* in12, const void* in13, const void* in14, const void* in15,
    const void* in16, const void* in17, const void* in18, const void* in19,
    const void* in20)
{
  __shared__ int sflag;
  const int tid = threadIdx.x;
  if (tid < 64){
    const us* u = (const us*)in0;
    int cnt = 0;
    #pragma unroll
    for (int j = 0; j < 8; ++j){
      us v = u[2*(tid*8+j)];          // even us-index: fp32 low-halves if fp32
      int e = (v >> 7) & 0xff;
      cnt += (e >= 143);              // |x| >= 2^16 as bf16: impossible for real data
    }
    #pragma unroll
    for (int off = 32; off; off >>= 1) cnt += __shfl_xor(cnt, off);
    if (tid == 0){ sflag = (cnt > 16); g_isf32 = (cnt > 16); }
  }
  __syncthreads();
  const int isf32 = sflag;
  const int g0 = blockIdx.x*256 + tid;
  const int gs = gridDim.x*256;
  #define CVT(src, dst, n) \
    for (int i = g0; i < (n); i += gs) \
      dst[i] = isf32 ? ((const float*)(src))[i] : b2f(((const us*)(src))[i]);
  CVT(in0,  g_imf, 16000)
  CVT(in1,  g_c,   1500)
  CVT(in2,  g_ct,  1500)
  CVT(in3,  g_wc1, 2048)
  CVT(in4,  g_bc1, 64)
  CVT(in5,  g_wc2, 8192)
  CVT(in6,  g_bc2, 128)
  CVT(in7,  g_wps1,32768)
  CVT(in8,  g_bps1,256)
  CVT(in9,  g_wps2,32768)
  CVT(in10, g_bps2,128)
  CVT(in11, g_wp1, 192)
  CVT(in12, g_bp1, 64)
  CVT(in13, g_wp2, 8192)
  CVT(in14, g_bp2, 128)
  CVT(in15, g_wfc1,16384)
  CVT(in16, g_bfc1,64)
  CVT(in17, g_wfc2,10240)
  CVT(in18, g_bfc2,64)
  CVT(in19, g_wfc, 8192)
  CVT(in20, g_bfc, 64)
  #undef CVT
}

// K1: blocks 0..249   = KNN (1 query per wave, 4/block) + exp(-dist) emission.
//     blocks 250..749 = per-point conv chains, ONE point per block.
__global__ __launch_bounds__(256) void k1()
{
  __shared__ __align__(16) float sm[1504];
  const int tid = threadIdx.x;
  const int b = blockIdx.x;
  if (b < 250) {
    // ---------------- KNN + exp numerators ----------------
    const int dir = (b >= 125);            // 0: query=c, ref=ct ; 1: query=ct, ref=c
    const float* refp = dir ? g_c : g_ct;
    const float* qp   = dir ? g_ct : g_c;
    int* outp = dir ? g_inds_tc : g_inds;
    float* logp = dir ? g_logB : g_logA;
    for (int e = tid; e < 1500; e += 256) sm[e] = refp[e];
    __syncthreads();
    const int lane = tid & 63;
    const int wv = tid >> 6;
    const int q = b*4 + wv;
    const int qi = q - (dir ? 500 : 0);
    float qx = qp[qi*3+0], qy = qp[qi*3+1], qz = qp[qi*3+2];
    // exact numpy op order: sum(q^2) - 2*dot + sum(r^2)
    float sq = __fadd_rn(__fadd_rn(__fmul_rn(qx,qx),__fmul_rn(qy,qy)),__fmul_rn(qz,qz));
    const u64 SENT = 0xFFFFFFFF00000000ull;   // sentinel carries valid idx 0
    u64 a0=SENT,a1=SENT,a2=SENT,a3=SENT,a4=SENT,a5=SENT,a6=SENT,a7=SENT;
    for (int j = lane; j < NN; j += 64){
      float rx = sm[j*3+0], ry = sm[j*3+1], rz = sm[j*3+2];
      float dt = __fadd_rn(__fadd_rn(__fmul_rn(qx,rx),__fmul_rn(qy,ry)),__fmul_rn(qz,rz));
      float sr = __fadd_rn(__fadd_rn(__fmul_rn(rx,rx),__fmul_rn(ry,ry)),__fmul_rn(rz,rz));
      float d2 = __fadd_rn(__fsub_rn(sq, __fmul_rn(2.f,dt)), sr);
      u32 fb = __float_as_uint(d2);
      fb = (fb & 0x80000000u) ? ~fb : (fb | 0x80000000u);   // monotone float->uint
      u64 key = ((u64)fb << 32) | (u32)j;
      if (key < a0){ u64 t=a0; a0=key; key=t; }
      if (key < a1){ u64 t=a1; a1=key; key=t; }
      if (key < a2){ u64 t=a2; a2=key; key=t; }
      if (key < a3){ u64 t=a3; a3=key; key=t; }
      if (key < a4){ u64 t=a4; a4=key; key=t; }
      if (key < a5){ u64 t=a5; a5=key; key=t; }
      if (key < a6){ u64 t=a6; a6=key; key=t; }
      if (key < a7){ u64 t=a7; a7=key; key=t; }
    }
    #pragma unroll
    for (int r8 = 0; r8 < 8; ++r8){
      u64 m = a0;
      #pragma unroll
      for (int off = 32; off; off >>= 1){
        u64 o = __shfl_xor(m, off);
        if (o < m) m = o;
      }
      bool mine = (a0 == m);
      a0 = mine ? a1 : a0;  a1 = mine ? a2 : a1;  a2 = mine ? a3 : a2;
      a3 = mine ? a4 : a3;  a4 = mine ? a5 : a4;  a5 = mine ? a6 : a5;
      a6 = mine ? a7 : a6;  a7 = mine ? SENT : a7;
      if (lane == 0){
        int idx = (int)(m & 0xffffffffu);
        outp[qi*8 + r8] = idx;
        // softmax numerator exp(-dist), reference dist order
        float rx = sm[idx*3+0], ry = sm[idx*3+1], rz = sm[idx*3+2];
        float dx = __fsub_rn(qx,rx), dy = __fsub_rn(qy,ry), dz = __fsub_rn(qz,rz);
        float s2 = __fadd_rn(__fadd_rn(__fmul_rn(dx,dx),__fmul_rn(dy,dy)),__fmul_rn(dz,dz));
        logp[qi*8 + r8] = expf(-sqrtf(s2));   // in [4.5e-5,1]: shift-free safe
      }
    }
  } else {
    // ---------------- per-point chain, one point ----------------
    const int p = b - 250;
    float* sx  = sm;          // 3   (c column)
    float* sxi = sm + 4;      // 32  (imf column)
    float* h1  = sm + 64;     // 64
    float* cf  = sm + 128;    // 128
    float* h2  = sm + 256;    // 256
    float* hy  = sm + 512;    // 64
    if (tid < 3)  sx[tid] = g_c[p*3 + tid];
    if (tid >= 32 && tid < 64) sxi[tid-32] = g_imf[(tid-32)*NN + p];
    __syncthreads();
    // stage1: h1 = lrelu(pconv1 @ x + b)   (threads 0..63)
    if (tid < 64){
      float acc = g_bp1[tid];
      acc += g_wp1[tid*3+0]*sx[0];
      acc += g_wp1[tid*3+1]*sx[1];
      acc += g_wp1[tid*3+2]*sx[2];
      h1[tid] = lrelu(acc);
    }
    __syncthreads();
    // stage2 (t0..127): cf = pconv2 @ h1 + b  (dot64)
    // stage5 (t128..191): hy = lrelu(conv1 @ imf + b)  (dot32) — independent
    if (tid < 128){
      int r = tid;
      float acc = g_bp2[r];
      const float4* wrow = (const float4*)(g_wp2 + (size_t)r*64);
      #pragma unroll 8
      for (int c4=0; c4<16; ++c4) acc += dot4(wrow[c4], h1 + c4*4);
      cf[r] = acc;
      g_cfw[(size_t)p*128 + r] = acc;
    } else if (tid < 192){
      int r = tid - 128;
      float acc = g_bc1[r];
      const float4* wrow = (const float4*)(g_wc1 + (size_t)r*32);
      #pragma unroll 8
      for (int c4=0; c4<8; ++c4) acc += dot4(wrow[c4], sxi + c4*4);
      hy[r] = lrelu(acc);
    }
    __syncthreads();
    // stage3 (all 256): h2 = lrelu(psconv1 @ cf + b)  (dot128)
    {
      float acc = g_bps1[tid];
      const float4* wrow = (const float4*)(g_wps1 + (size_t)tid*128);
      #pragma unroll 8
      for (int c4=0; c4<32; ++c4) acc += dot4(wrow[c4], cf + c4*4);
      h2[tid] = lrelu(acc);
    }
    __syncthreads();
    // stage4 (t0..127): Z = psconv2 @ h2 + b  (dot256)
    // stage6 (t128..255): Y = conv2 @ hy + b  (dot64)
    if (tid < 128){
      int r = tid;
      float acc = g_bps2[r];
      const float4* wrow = (const float4*)(g_wps2 + (size_t)r*256);
      #pragma unroll 8
      for (int c4=0; c4<64; ++c4) acc += dot4(wrow[c4], h2 + c4*4);
      g_Zw[(size_t)p*128 + r] = acc;
    } else {
      int r = tid - 128;
      float acc = g_bc2[r];
      const float4* wrow = (const float4*)(g_wc2 + (size_t)r*64);
      #pragma unroll 8
      for (int c4=0; c4<16; ++c4) acc += dot4(wrow[c4], hy + c4*4);
      g_Yw[(size_t)p*128 + r] = acc;
    }
  }
}

// K3: ONE point per block (500 blocks): per-block redundant softmax-sum over
// k1's precomputed exp numerators (L2-hot, removes the old k2 dispatch),
// then weighted gather-mean + fc chain -> out.
__global__ __launch_bounds__(256) void k3(void* outv)
{
  __shared__ __align__(16) float sm[592];
  __shared__ float redA[4], redB[4];
  float* sb1 = sm;          // 256 : [sf | cf]
  float* sb2 = sm + 256;    // 160 : [sfp | imf]
  float* sg  = sm + 416;    // 128 : lrelu([f2 ; f1])
  float* swa = sm + 544;    // 8
  float* swb = sm + 552;    // 8
  int* sia = (int*)(sm + 560);  // 8
  int* sib = (int*)(sm + 568);  // 8
  const int tid = threadIdx.x;
  const int lane = tid & 63, wv = tid >> 6;
  const int p = blockIdx.x;
  const int of32 = g_isf32;
  // ---- block-redundant softmax denominators (tree-sum; ~1e-7 vs np order) ----
  float sA = 0.f, sB = 0.f;
  {
    const float4* la = (const float4*)g_logA;
    const float4* lb = (const float4*)g_logB;
    for (int e = tid; e < 1000; e += 256){
      float4 a = la[e]; sA += (a.x + a.y) + (a.z + a.w);
      float4 b = lb[e]; sB += (b.x + b.y) + (b.z + b.w);
    }
  }
  #pragma unroll
  for (int off = 32; off; off >>= 1){
    sA += __shfl_xor(sA, off);
    sB += __shfl_xor(sB, off);
  }
  if (lane == 0){ redA[wv] = sA; redB[wv] = sB; }
  // ---- staging (overlaps with reduction; barrier below covers both) ----
  if (tid < 8){
    sia[tid] = clampi(g_inds[p*8 + tid]);
    sib[tid] = clampi(g_inds_tc[p*8 + tid]);
  }
  if (tid >= 64 && tid < 192) sb1[128 + (tid-64)] = g_cfw[(size_t)p*128 + (tid-64)];
  if (tid >= 192 && tid < 224) sb2[128 + (tid-192)] = g_imf[(tid-192)*NN + p];
  __syncthreads();
  if (tid < 8){
    float totA = (redA[0] + redA[1]) + (redA[2] + redA[3]);
    float totB = (redB[0] + redB[1]) + (redB[2] + redB[3]);
    swa[tid] = g_logA[p*8 + tid] / totA;
    swb[tid] = g_logB[p*8 + tid] / totB;
  }
  __syncthreads();
  // gather-mean: t0..127 -> sf (from Y), t128..255 -> sfp (from Z)
  if (tid < 128){
    int r = tid;
    float acc = 0.f;
    #pragma unroll
    for (int j=0;j<8;++j) acc += swa[j] * g_Yw[(size_t)sia[j]*128 + r];
    sb1[r] = acc * 0.125f;
  } else {
    int r = tid - 128;
    float acc = 0.f;
    #pragma unroll
    for (int j=0;j<8;++j) acc += swb[j] * g_Zw[(size_t)sib[j]*128 + r];
    sb2[r] = acc * 0.125f;
  }
  __syncthreads();
  // f1 (t0..63, dot256) ; f2 (t64..127, dot160); g = lrelu([f2 ; f1])
  if (tid < 64){
    int r = tid;
    float a1 = g_bfc1[r];
    const float4* w1 = (const float4*)(g_wfc1 + (size_t)r*256);
    #pragma unroll 8
    for (int c4=0; c4<64; ++c4) a1 += dot4(w1[c4], sb1 + c4*4);
    sg[64 + r] = lrelu(a1);
  } else if (tid < 128){
    int r = tid - 64;
    float a2 = g_bfc2[r];
    const float4* w2 = (const float4*)(g_wfc2 + (size_t)r*160);
    #pragma unroll 8
    for (int c4=0; c4<40; ++c4) a2 += dot4(w2[c4], sb2 + c4*4);
    sg[r] = lrelu(a2);
  }
  __syncthreads();
  // out = wfc @ g + b (t0..63, dot128)
  if (tid < 64){
    int r = tid;
    float a = g_bfc[r];
    const float4* w3 = (const float4*)(g_wfc + (size_t)r*128);
    #pragma unroll 8
    for (int c4=0; c4<32; ++c4) a += dot4(w3[c4], sg + c4*4);
    if (of32) ((float*)outv)[r*NN + p] = a;
    else      ((us*)outv)[r*NN + p] = f2b(a);
  }
}

extern "C" void kernel_launch(void* const* d_in, const int* in_sizes, int n_in,
                              void* d_out, int out_size, void* d_ws, size_t ws_size,
                              hipStream_t stream)
{
  (void)d_ws; (void)ws_size; (void)in_sizes; (void)n_in; (void)out_size;
  k0<<<64, 256, 0, stream>>>(
    d_in[0], d_in[1], d_in[2], d_in[3], d_in[4], d_in[5], d_in[6],
    d_in[7], d_in[8], d_in[9], d_in[10], d_in[11], d_in[12], d_in[13],
    d_in[14], d_in[15], d_in[16], d_in[17], d_in[18], d_in[19], d_in[20]);
  k1<<<750, 256, 0, stream>>>();
  k3<<<500, 256, 0, stream>>>(d_out);
}